// Round 4
// baseline (180.775 us; speedup 1.0000x reference)
//
#include <hip/hip_runtime.h>
#include <cmath>
#include <complex>

#define T_LEN   131072
#define B_ROWS  96
#define CHUNK   32                         // output samples per thread
#define WARM    64                         // warm-up samples (0.878^64 ~ 2.4e-4)
#define WSEG    2048                       // output samples per wave (64 lanes * CHUNK)
#define WSTG    (WSEG + WARM)              // 2112 staged floats per wave
#define WF4     (WSTG / 4)                 // 528 float4 per wave (8-aligned: 66*8)
#define WPW     (T_LEN / WSEG)             // 64 waves per row
#define TOTAL_WAVES (B_ROWS * WPW)         // 6144
#define BLOCK   256
#define WVB     4                          // waves per block
#define GRID    (TOTAL_WAVES / WVB)        // 1536

struct Coefs {
  float b0, b1, b2, b3, b4, b5, b6;
  float a1, a2, a3, a4, a5, a6;
  float invN;
};

// XOR swizzle at float4 granularity within each wave's 8-aligned LDS slice.
// Staging (lane-stride 1 in f4) and window reads (lane-stride 8 in f4) both
// hit all 8 bank-groups per 8-lane service group -> conflict-free b128.
__device__ __forceinline__ int swz(int f) { return f ^ ((f >> 3) & 7); }

// One DF2T step, matching the reference update:
//   y   = b0*x + z0
//   z_i = z_{i+1} + b_{i+1}*x - a_{i+1}*y   (z_6 == 0)
#define LP_STEP(x, ACC)                                  \
  {                                                      \
    float y = fmaf(cf.b0, (x), z0);                      \
    ACC;                                                 \
    z0 = fmaf(-cf.a1, y, fmaf(cf.b1, (x), z1));          \
    z1 = fmaf(-cf.a2, y, fmaf(cf.b2, (x), z2));          \
    z2 = fmaf(-cf.a3, y, fmaf(cf.b3, (x), z3));          \
    z3 = fmaf(-cf.a4, y, fmaf(cf.b4, (x), z4));          \
    z4 = fmaf(-cf.a5, y, fmaf(cf.b5, (x), z5));          \
    z5 = fmaf(-cf.a6, y, cf.b6 * (x));                   \
  }

__global__ __launch_bounds__(BLOCK, 4) void lp_mae_kernel(
    const float* __restrict__ out_p, const float* __restrict__ tgt_p,
    float* __restrict__ dout, Coefs cf)
{
  // 4 waves * 528 float4 = 33792 B -> 4 blocks/CU, 16 waves/CU.
  __shared__ float4 xs[WVB * WF4];

  const int lane = threadIdx.x & 63;
  const int wv   = threadIdx.x >> 6;
  const int wid  = blockIdx.x * WVB + wv;
  const int row  = wid >> 6;               // wid / WPW
  const int ws   = wid & (WPW - 1);        // wave segment within row

  float4* lds = xs + wv * WF4;             // this wave's private slice

  const size_t outstart = (size_t)row * T_LEN + (size_t)ws * WSEG;
  // Staged region [outstart - WARM, outstart + WSEG). ws==0: zero-fill prefix
  // (filtering zeros keeps zero state -> exact semantics, no OOB deref).
  const float4* po = (const float4*)(out_p + outstart - WARM);
  const float4* pt = (const float4*)(tgt_p + outstart - WARM);
  const bool first = (ws == 0);

  // ---- Stage this wave's diff region: coalesced float4 loads, b128 writes.
  // 528 f4 / 64 lanes = 8 full rounds + one 16-lane round. NO BARRIER:
  // same-wave write->read, compiler inserts the waitcnt.
  #pragma unroll
  for (int r = 0; r < 9; ++r) {
    const int l = r * 64 + lane;
    if (l < WF4) {
      float4 d;
      if (first && l < (WARM / 4)) {
        d = make_float4(0.f, 0.f, 0.f, 0.f);
      } else {
        float4 a = po[l];
        float4 b = pt[l];
        d.x = a.x - b.x; d.y = a.y - b.y;
        d.z = a.z - b.z; d.w = a.w - b.w;
      }
      lds[swz(l)] = d;
    }
  }

  // ---- IIR over this lane's 96-sample window (24 f4, lane-stride 8) ----
  const int base = lane * 8;
  float z0 = 0.f, z1 = 0.f, z2 = 0.f, z3 = 0.f, z4 = 0.f, z5 = 0.f;
  float sum = 0.f;

  #pragma unroll
  for (int k = 0; k < WARM / 4; ++k) {     // 64 warm-up samples, discard y
    float4 x = lds[swz(base + k)];
    LP_STEP(x.x, );
    LP_STEP(x.y, );
    LP_STEP(x.z, );
    LP_STEP(x.w, );
  }
  #pragma unroll
  for (int k = WARM / 4; k < 24; ++k) {    // 32 owned samples, accumulate |y|
    float4 x = lds[swz(base + k)];
    LP_STEP(x.x, sum += fabsf(y));
    LP_STEP(x.y, sum += fabsf(y));
    LP_STEP(x.z, sum += fabsf(y));
    LP_STEP(x.w, sum += fabsf(y));
  }

  // ---- Wave64 shuffle reduce -> one atomic per wave (wave retires free) ----
  #pragma unroll
  for (int off = 32; off > 0; off >>= 1)
    sum += __shfl_down(sum, off);
  if (lane == 0)
    atomicAdd(dout, sum * cf.invN);
}

extern "C" void kernel_launch(void* const* d_in, const int* in_sizes, int n_in,
                              void* d_out, int out_size, void* d_ws, size_t ws_size,
                              hipStream_t stream) {
  (void)in_sizes; (void)n_in; (void)d_ws; (void)ws_size; (void)out_size;

  const float* out_p = (const float*)d_in[0];
  const float* tgt_p = (const float*)d_in[1];
  float* dout = (float*)d_out;

  // ---- Host-side coefficient computation (mirrors _butter_lowpass in f64,
  // then casts to f32 exactly like the reference's .astype(np.float32)). ----
  using cd = std::complex<double>;
  const int order = 6;
  const double wn = 4000.0 / 24000.0;          // CUTOFF / (0.5 * SAMPLE_RATE)
  const double fs = 2.0;
  const double warped = 2.0 * fs * std::tan(M_PI * wn / fs);

  cd p[6];
  for (int k = 0; k < order; ++k) {
    int m = -order + 1 + 2 * k;                // [-5,-3,-1,1,3,5]
    p[k] = -std::exp(cd(0.0, M_PI * m / (2.0 * order))) * warped;
  }
  double kgain = std::pow(warped, (double)order);
  const double fs2 = 2.0 * fs;

  cd pz[6];
  cd prodden(1.0, 0.0);
  for (int k = 0; k < order; ++k) {
    pz[k] = (fs2 + p[k]) / (fs2 - p[k]);
    prodden *= (fs2 - p[k]);
  }
  double kz = kgain * std::real(1.0 / prodden);

  // b = kz * poly(-ones(6)) = kz * binomial(6, i)
  const double binom[7] = {1, 6, 15, 20, 15, 6, 1};
  double bd[7];
  for (int i = 0; i < 7; ++i) bd[i] = kz * binom[i];

  // a = real(poly(pz))
  cd ac[7];
  ac[0] = cd(1.0, 0.0);
  for (int i = 1; i < 7; ++i) ac[i] = cd(0.0, 0.0);
  for (int k = 0; k < order; ++k)
    for (int i = k + 1; i >= 1; --i)
      ac[i] = ac[i] - pz[k] * ac[i - 1];

  Coefs cf;
  cf.b0 = (float)bd[0]; cf.b1 = (float)bd[1]; cf.b2 = (float)bd[2];
  cf.b3 = (float)bd[3]; cf.b4 = (float)bd[4]; cf.b5 = (float)bd[5];
  cf.b6 = (float)bd[6];
  cf.a1 = (float)std::real(ac[1]); cf.a2 = (float)std::real(ac[2]);
  cf.a3 = (float)std::real(ac[3]); cf.a4 = (float)std::real(ac[4]);
  cf.a5 = (float)std::real(ac[5]); cf.a6 = (float)std::real(ac[6]);
  cf.invN = 1.0f / (float)((double)B_ROWS * (double)T_LEN);

  hipMemsetAsync(d_out, 0, sizeof(float), stream);
  lp_mae_kernel<<<GRID, BLOCK, 0, stream>>>(out_p, tgt_p, dout, cf);
}

// Round 5
// 178.093 us; speedup vs baseline: 1.0151x; 1.0151x over previous
//
#include <hip/hip_runtime.h>
#include <cmath>
#include <complex>

#define T_LEN   131072
#define B_ROWS  96
#define CHUNK   32                        // output samples per thread
#define WARM    64                        // warm-up samples (0.878^64 ~ 2.4e-4)
#define SEG     8192                      // samples per block (256 threads * CHUNK)
#define NSEG    (T_LEN / SEG)             // 16 segments per row
#define NLDS    (SEG + WARM)              // 8256 staged samples per block
#define NF4     (NLDS / 4)                // 2064 float4 slots
#define BLOCK   256
#define RND     8                         // full staging rounds (8*256 = 2048 f4)
#define TAILN   (NF4 - RND * BLOCK)       // 16 ragged f4
#define WPT     24                        // float4s per thread window (96 samples)

struct Coefs {
  float b0, b1, b2, b3, b4, b5, b6;
  float a1, a2, a3, a4, a5, a6;
  float invN;
};

// XOR swizzle at float4 granularity: bijection within each aligned 8-float4
// group. Staging writes (lane-stride 1 in f) and window reads (lane-stride 8
// in f) both spread across all 8 bank-groups -> conflict-free b128.
__device__ __forceinline__ int swz(int f) { return f ^ ((f >> 3) & 7); }

// One DF2T step, matching the reference update:
//   y   = b0*x + z0
//   z_i = z_{i+1} + b_{i+1}*x - a_{i+1}*y   (z_6 == 0)
#define LP_STEP(x, ACC)                                  \
  {                                                      \
    float y = fmaf(cf.b0, (x), z0);                      \
    ACC;                                                 \
    z0 = fmaf(-cf.a1, y, fmaf(cf.b1, (x), z1));          \
    z1 = fmaf(-cf.a2, y, fmaf(cf.b2, (x), z2));          \
    z2 = fmaf(-cf.a3, y, fmaf(cf.b3, (x), z3));          \
    z3 = fmaf(-cf.a4, y, fmaf(cf.b4, (x), z4));          \
    z4 = fmaf(-cf.a5, y, fmaf(cf.b5, (x), z5));          \
    z5 = fmaf(-cf.a6, y, cf.b6 * (x));                   \
  }

__global__ __launch_bounds__(BLOCK, 4) void lp_mae_kernel(
    const float* __restrict__ out_p, const float* __restrict__ tgt_p,
    float* __restrict__ dout, Coefs cf)
{
  __shared__ float4 xs[NF4];              // 33 KB -> 4 blocks/CU (LDS cap)

  const int blk = blockIdx.x;
  const int row = blk >> 4;               // blk / NSEG
  const int s   = blk & (NSEG - 1);       // segment within row
  const bool first = (s == 0);

  const size_t segbase = (size_t)row * T_LEN + (size_t)s * SEG;
  // Staged region [segbase - WARM, segbase + SEG). first: prefix zero-filled
  // (filtering zeros keeps zero state -> exact), loads clamped in-bounds.
  const float4* po = (const float4*)(out_p + segbase - WARM);
  const float4* pt = (const float4*)(tgt_p + segbase - WARM);

  // ---- Phase 1a: batch ALL staging loads into registers (deep pipeline).
  // 16 loads live at once (64 VGPRs) -> ~1-2 memory latencies, not ~8.
  float4 a[RND], b[RND];
  #pragma unroll
  for (int r = 0; r < RND; ++r) {
    const int g  = r * BLOCK + threadIdx.x;
    const int gl = (first && g < (WARM / 4)) ? g + (WARM / 4) : g; // in-bounds dummy
    a[r] = po[gl];
    b[r] = pt[gl];
  }
  float4 at, bt;
  const bool tl = threadIdx.x < TAILN;
  const int  gt = RND * BLOCK + threadIdx.x;
  if (tl) { at = po[gt]; bt = pt[gt]; }

  // ---- Phase 1b: diff + swizzled b128 writes ----
  #pragma unroll
  for (int r = 0; r < RND; ++r) {
    const int g = r * BLOCK + threadIdx.x;
    float4 d;
    d.x = a[r].x - b[r].x; d.y = a[r].y - b[r].y;
    d.z = a[r].z - b[r].z; d.w = a[r].w - b[r].w;
    if (first && g < (WARM / 4)) d = make_float4(0.f, 0.f, 0.f, 0.f);
    xs[swz(g)] = d;
  }
  if (tl) {
    float4 d;
    d.x = at.x - bt.x; d.y = at.y - bt.y;
    d.z = at.z - bt.z; d.w = at.w - bt.w;
    xs[swz(gt)] = d;
  }
  __syncthreads();

  // ---- Phase 2: pull this thread's 96-sample window into registers ----
  float4 w[WPT];
  #pragma unroll
  for (int j = 0; j < WPT; ++j)
    w[j] = xs[swz(threadIdx.x * 8 + j)];

  // ---- Phase 3: IIR over the window, pure register compute ----
  float z0 = 0.f, z1 = 0.f, z2 = 0.f, z3 = 0.f, z4 = 0.f, z5 = 0.f;
  float sum = 0.f;

  #pragma unroll
  for (int j = 0; j < WARM / 4; ++j) {    // 64 warm-up samples, discard y
    LP_STEP(w[j].x, );
    LP_STEP(w[j].y, );
    LP_STEP(w[j].z, );
    LP_STEP(w[j].w, );
  }
  #pragma unroll
  for (int j = WARM / 4; j < WPT; ++j) {  // 32 owned samples, accumulate |y|
    LP_STEP(w[j].x, sum += fabsf(y));
    LP_STEP(w[j].y, sum += fabsf(y));
    LP_STEP(w[j].z, sum += fabsf(y));
    LP_STEP(w[j].w, sum += fabsf(y));
  }

  // ---- Phase 4: wave64 shuffle reduce -> one atomic per wave ----
  #pragma unroll
  for (int off = 32; off > 0; off >>= 1)
    sum += __shfl_down(sum, off);
  if ((threadIdx.x & 63) == 0)
    atomicAdd(dout, sum * cf.invN);
}

extern "C" void kernel_launch(void* const* d_in, const int* in_sizes, int n_in,
                              void* d_out, int out_size, void* d_ws, size_t ws_size,
                              hipStream_t stream) {
  (void)in_sizes; (void)n_in; (void)d_ws; (void)ws_size; (void)out_size;

  const float* out_p = (const float*)d_in[0];
  const float* tgt_p = (const float*)d_in[1];
  float* dout = (float*)d_out;

  // ---- Host-side coefficient computation (mirrors _butter_lowpass in f64,
  // then casts to f32 exactly like the reference's .astype(np.float32)). ----
  using cd = std::complex<double>;
  const int order = 6;
  const double wn = 4000.0 / 24000.0;          // CUTOFF / (0.5 * SAMPLE_RATE)
  const double fs = 2.0;
  const double warped = 2.0 * fs * std::tan(M_PI * wn / fs);

  cd p[6];
  for (int k = 0; k < order; ++k) {
    int m = -order + 1 + 2 * k;                // [-5,-3,-1,1,3,5]
    p[k] = -std::exp(cd(0.0, M_PI * m / (2.0 * order))) * warped;
  }
  double kgain = std::pow(warped, (double)order);
  const double fs2 = 2.0 * fs;

  cd pz[6];
  cd prodden(1.0, 0.0);
  for (int k = 0; k < order; ++k) {
    pz[k] = (fs2 + p[k]) / (fs2 - p[k]);
    prodden *= (fs2 - p[k]);
  }
  double kz = kgain * std::real(1.0 / prodden);

  // b = kz * poly(-ones(6)) = kz * binomial(6, i)
  const double binom[7] = {1, 6, 15, 20, 15, 6, 1};
  double bd[7];
  for (int i = 0; i < 7; ++i) bd[i] = kz * binom[i];

  // a = real(poly(pz))
  cd ac[7];
  ac[0] = cd(1.0, 0.0);
  for (int i = 1; i < 7; ++i) ac[i] = cd(0.0, 0.0);
  for (int k = 0; k < order; ++k)
    for (int i = k + 1; i >= 1; --i)
      ac[i] = ac[i] - pz[k] * ac[i - 1];

  Coefs cf;
  cf.b0 = (float)bd[0]; cf.b1 = (float)bd[1]; cf.b2 = (float)bd[2];
  cf.b3 = (float)bd[3]; cf.b4 = (float)bd[4]; cf.b5 = (float)bd[5];
  cf.b6 = (float)bd[6];
  cf.a1 = (float)std::real(ac[1]); cf.a2 = (float)std::real(ac[2]);
  cf.a3 = (float)std::real(ac[3]); cf.a4 = (float)std::real(ac[4]);
  cf.a5 = (float)std::real(ac[5]); cf.a6 = (float)std::real(ac[6]);
  cf.invN = 1.0f / (float)((double)B_ROWS * (double)T_LEN);

  hipMemsetAsync(d_out, 0, sizeof(float), stream);
  lp_mae_kernel<<<B_ROWS * NSEG, BLOCK, 0, stream>>>(out_p, tgt_p, dout, cf);
}

// Round 6
// 126.969 us; speedup vs baseline: 1.4238x; 1.4026x over previous
//
#include <hip/hip_runtime.h>
#include <cmath>
#include <complex>

#define T_LEN   131072
#define B_ROWS  96
#define CHUNK   32                        // output samples per thread
#define WARM    64                        // warm-up samples (0.878^64 ~ 2.4e-4)
#define SEG     8192                      // samples per block (256 threads * CHUNK)
#define NSEG    (T_LEN / SEG)             // 16 segments per row
#define NLDS    (SEG + WARM)              // 8256 staged samples per block
#define NF4     (NLDS / 4)                // 2064 float4 slots
#define BLOCK   256
#define WPT     24                        // float4s per thread window (96 samples)
#define GRID    (B_ROWS * NSEG)           // 1536 blocks

struct Coefs {
  float b0, b1, b2, b3, b4, b5, b6;
  float a1, a2, a3, a4, a5, a6;
  float invN;
};

// XOR swizzle at float4 granularity: bijection within each aligned 8-float4
// group. Staging writes (lane-stride 1 in f) and window reads (lane-stride 8
// in f) both spread across all 8 bank-groups -> conflict-free b128.
__device__ __forceinline__ int swz(int f) { return f ^ ((f >> 3) & 7); }

// One DF2T step, matching the reference update:
//   y   = b0*x + z0
//   z_i = z_{i+1} + b_{i+1}*x - a_{i+1}*y   (z_6 == 0)
#define LP_STEP(x, ACC)                                  \
  {                                                      \
    float y = fmaf(cf.b0, (x), z0);                      \
    ACC;                                                 \
    z0 = fmaf(-cf.a1, y, fmaf(cf.b1, (x), z1));          \
    z1 = fmaf(-cf.a2, y, fmaf(cf.b2, (x), z2));          \
    z2 = fmaf(-cf.a3, y, fmaf(cf.b3, (x), z3));          \
    z3 = fmaf(-cf.a4, y, fmaf(cf.b4, (x), z4));          \
    z4 = fmaf(-cf.a5, y, fmaf(cf.b5, (x), z5));          \
    z5 = fmaf(-cf.a6, y, cf.b6 * (x));                   \
  }

__global__ __launch_bounds__(BLOCK, 4) void lp_mae_kernel(
    const float* __restrict__ out_p, const float* __restrict__ tgt_p,
    float* __restrict__ partial, Coefs cf)
{
  __shared__ float4 xs[NF4];              // 33 KB -> 4 blocks/CU (LDS cap)
  __shared__ float red[BLOCK / 64];

  const int blk = blockIdx.x;
  const int row = blk >> 4;               // blk / NSEG
  const int s   = blk & (NSEG - 1);       // segment within row

  const size_t segbase = (size_t)row * T_LEN + (size_t)s * SEG;
  // Staged region [segbase - WARM, segbase + SEG). For s==0 the prefix is
  // zero-filled (filtering zeros keeps zero state -> exact semantics).
  const float4* po = (const float4*)(out_p + segbase - WARM);
  const float4* pt = (const float4*)(tgt_p + segbase - WARM);

  // ---- Stage diff into LDS: coalesced global float4 loads, b128 writes ----
  for (int g = threadIdx.x; g < NF4; g += BLOCK) {
    float4 d;
    if (s == 0 && g < (WARM / 4)) {
      d = make_float4(0.f, 0.f, 0.f, 0.f);
    } else {
      float4 xo = po[g];
      float4 xt = pt[g];
      d.x = xo.x - xt.x; d.y = xo.y - xt.y;
      d.z = xo.z - xt.z; d.w = xo.w - xt.w;
    }
    xs[swz(g)] = d;
  }
  __syncthreads();

  // ---- Pull this thread's 96-sample window into registers (24x b128) ----
  float4 w[WPT];
  #pragma unroll
  for (int j = 0; j < WPT; ++j)
    w[j] = xs[swz(threadIdx.x * 8 + j)];

  // ---- IIR over the window, pure register compute ----
  float z0 = 0.f, z1 = 0.f, z2 = 0.f, z3 = 0.f, z4 = 0.f, z5 = 0.f;
  float sum = 0.f;

  #pragma unroll
  for (int j = 0; j < WARM / 4; ++j) {    // 64 warm-up samples, discard y
    LP_STEP(w[j].x, );
    LP_STEP(w[j].y, );
    LP_STEP(w[j].z, );
    LP_STEP(w[j].w, );
  }
  #pragma unroll
  for (int j = WARM / 4; j < WPT; ++j) {  // 32 owned samples, accumulate |y|
    LP_STEP(w[j].x, sum += fabsf(y));
    LP_STEP(w[j].y, sum += fabsf(y));
    LP_STEP(w[j].z, sum += fabsf(y));
    LP_STEP(w[j].w, sum += fabsf(y));
  }

  // ---- Wave64 shuffle reduce -> LDS -> ONE PLAIN STORE per block ----
  // (No atomics: 1536 disjoint addresses. R3->R5 evidence says same-address
  //  atomicAdd serializes at ~15ns each and was the hidden tail.)
  #pragma unroll
  for (int off = 32; off > 0; off >>= 1)
    sum += __shfl_down(sum, off);
  if ((threadIdx.x & 63) == 0)
    red[threadIdx.x >> 6] = sum;
  __syncthreads();
  if (threadIdx.x == 0)
    partial[blk] = red[0] + red[1] + red[2] + red[3];
}

// Final reduction: 1536 partials -> d_out. One block, ~6KB of reads.
__global__ __launch_bounds__(BLOCK) void lp_reduce_kernel(
    const float* __restrict__ partial, float* __restrict__ dout, float invN)
{
  __shared__ float red[BLOCK / 64];
  float sum = 0.f;
  for (int i = threadIdx.x; i < GRID; i += BLOCK)
    sum += partial[i];
  #pragma unroll
  for (int off = 32; off > 0; off >>= 1)
    sum += __shfl_down(sum, off);
  if ((threadIdx.x & 63) == 0)
    red[threadIdx.x >> 6] = sum;
  __syncthreads();
  if (threadIdx.x == 0)
    dout[0] = (red[0] + red[1] + red[2] + red[3]) * invN;
}

extern "C" void kernel_launch(void* const* d_in, const int* in_sizes, int n_in,
                              void* d_out, int out_size, void* d_ws, size_t ws_size,
                              hipStream_t stream) {
  (void)in_sizes; (void)n_in; (void)ws_size; (void)out_size;

  const float* out_p = (const float*)d_in[0];
  const float* tgt_p = (const float*)d_in[1];
  float* dout = (float*)d_out;
  float* partial = (float*)d_ws;           // 1536 floats of scratch

  // ---- Host-side coefficient computation (mirrors _butter_lowpass in f64,
  // then casts to f32 exactly like the reference's .astype(np.float32)). ----
  using cd = std::complex<double>;
  const int order = 6;
  const double wn = 4000.0 / 24000.0;          // CUTOFF / (0.5 * SAMPLE_RATE)
  const double fs = 2.0;
  const double warped = 2.0 * fs * std::tan(M_PI * wn / fs);

  cd p[6];
  for (int k = 0; k < order; ++k) {
    int m = -order + 1 + 2 * k;                // [-5,-3,-1,1,3,5]
    p[k] = -std::exp(cd(0.0, M_PI * m / (2.0 * order))) * warped;
  }
  double kgain = std::pow(warped, (double)order);
  const double fs2 = 2.0 * fs;

  cd pz[6];
  cd prodden(1.0, 0.0);
  for (int k = 0; k < order; ++k) {
    pz[k] = (fs2 + p[k]) / (fs2 - p[k]);
    prodden *= (fs2 - p[k]);
  }
  double kz = kgain * std::real(1.0 / prodden);

  // b = kz * poly(-ones(6)) = kz * binomial(6, i)
  const double binom[7] = {1, 6, 15, 20, 15, 6, 1};
  double bd[7];
  for (int i = 0; i < 7; ++i) bd[i] = kz * binom[i];

  // a = real(poly(pz))
  cd ac[7];
  ac[0] = cd(1.0, 0.0);
  for (int i = 1; i < 7; ++i) ac[i] = cd(0.0, 0.0);
  for (int k = 0; k < order; ++k)
    for (int i = k + 1; i >= 1; --i)
      ac[i] = ac[i] - pz[k] * ac[i - 1];

  Coefs cf;
  cf.b0 = (float)bd[0]; cf.b1 = (float)bd[1]; cf.b2 = (float)bd[2];
  cf.b3 = (float)bd[3]; cf.b4 = (float)bd[4]; cf.b5 = (float)bd[5];
  cf.b6 = (float)bd[6];
  cf.a1 = (float)std::real(ac[1]); cf.a2 = (float)std::real(ac[2]);
  cf.a3 = (float)std::real(ac[3]); cf.a4 = (float)std::real(ac[4]);
  cf.a5 = (float)std::real(ac[5]); cf.a6 = (float)std::real(ac[6]);
  cf.invN = 1.0f / (float)((double)B_ROWS * (double)T_LEN);

  lp_mae_kernel<<<GRID, BLOCK, 0, stream>>>(out_p, tgt_p, partial, cf);
  lp_reduce_kernel<<<1, BLOCK, 0, stream>>>(partial, dout, cf.invN);
}

// Round 7
// 124.285 us; speedup vs baseline: 1.4545x; 1.0216x over previous
//
#include <hip/hip_runtime.h>
#include <cmath>
#include <complex>

#define T_LEN   131072
#define B_ROWS  96
#define CHUNK   32                        // output samples per thread
#define WARM    64                        // warm-up samples (0.878^64 ~ 2.4e-4)
#define SEG     8192                      // samples per block (256 threads * CHUNK)
#define NSEG    (T_LEN / SEG)             // 16 segments per row
#define NLDS    (SEG + WARM)              // 8256 staged samples per block
#define NF4     (NLDS / 4)                // 2064 float4 slots per stream
#define BLOCK   256
#define WPT     24                        // float4s per thread window (96 samples)
#define GRID    (B_ROWS * NSEG)           // 1536 blocks
#define RNDS    33                        // 32 full 64-lane rounds + 16-lane tail

struct Coefs {
  float b0, b1, b2, b3, b4, b5, b6;
  float a1, a2, a3, a4, a5, a6;
  float invN;
};

// XOR swizzle at float4 granularity: involution within each aligned 8-float4
// (128 B) group. Applied to the GLOBAL address while global_load_lds writes
// LDS linearly: LDS[g] = G[swz(g)]  =>  LDS[swz(g)] = G[g]. Window reads at
// lane-stride 8 f4 then spread across all bank groups (conflict-free), and
// the permuted global loads stay within the same cache lines (coalesced).
__device__ __forceinline__ int swz(int f) { return f ^ ((f >> 3) & 7); }

// Async global->LDS DMA, 16 B per lane. LDS dest is wave-uniform base +
// lane*16 (m104/m108); global side is a normal per-lane address.
#define GLDS(gp, lp)                                                        \
  __builtin_amdgcn_global_load_lds(                                         \
      (const __attribute__((address_space(1))) void*)(gp),                  \
      (__attribute__((address_space(3))) void*)(lp), 16, 0, 0)

// One DF2T step, matching the reference update:
//   y   = b0*x + z0
//   z_i = z_{i+1} + b_{i+1}*x - a_{i+1}*y   (z_6 == 0)
#define LP_STEP(x, ACC)                                  \
  {                                                      \
    float y = fmaf(cf.b0, (x), z0);                      \
    ACC;                                                 \
    z0 = fmaf(-cf.a1, y, fmaf(cf.b1, (x), z1));          \
    z1 = fmaf(-cf.a2, y, fmaf(cf.b2, (x), z2));          \
    z2 = fmaf(-cf.a3, y, fmaf(cf.b3, (x), z3));          \
    z3 = fmaf(-cf.a4, y, fmaf(cf.b4, (x), z4));          \
    z4 = fmaf(-cf.a5, y, fmaf(cf.b5, (x), z5));          \
    z5 = fmaf(-cf.a6, y, cf.b6 * (x));                   \
  }

__global__ __launch_bounds__(BLOCK, 2) void lp_mae_kernel(
    const float* __restrict__ out_p, const float* __restrict__ tgt_p,
    const float4* __restrict__ zbuf,     // 16 zeroed float4s in d_ws
    float* __restrict__ partial, Coefs cf)
{
  __shared__ float4 ldsA[NF4];            // 2 x 33 KB -> 2 blocks/CU
  __shared__ float4 ldsB[NF4];
  __shared__ float red[BLOCK / 64];

  const int lane = threadIdx.x & 63;
  const int wv   = threadIdx.x >> 6;
  const int blk  = blockIdx.x;
  const int row  = blk >> 4;              // blk / NSEG
  const int s    = blk & (NSEG - 1);      // segment within row
  const bool first = (s == 0);

  const size_t segbase = (size_t)row * T_LEN + (size_t)s * SEG;
  // Staged region [segbase - WARM, segbase + SEG). For s==0 the 64-sample
  // prefix is sourced from the zero buffer (filtering zeros keeps zero
  // state -> exact semantics, no OOB deref).
  const float4* po = (const float4*)(out_p + segbase - WARM);
  const float4* pt = (const float4*)(tgt_p + segbase - WARM);

  // ---- Stage both streams via async DMA; all transfers in flight at once.
  // Wave wv issues rounds wv, wv+4, ... (LDS dest wave-uniform per round).
  for (int r = wv; r < RNDS; r += 4) {
    const int g = r * 64 + lane;
    if (g < NF4) {
      const float4* ga = po + swz(g);
      const float4* gb = pt + swz(g);
      if (first && r == 0 && lane < (WARM / 4)) {
        // swz maps [0,16) onto [0,16): these 16 linear slots are exactly the
        // logical zero-prefix. Redirect to the zeroed scratch.
        ga = zbuf + lane;
        gb = zbuf + lane;
      }
      GLDS(ga, ldsA + r * 64);
      GLDS(gb, ldsB + r * 64);
    }
  }
  __syncthreads();                        // compiler drains vmcnt here

  // ---- Pull this thread's 96-sample diff window into registers ----
  float4 w[WPT];
  #pragma unroll
  for (int j = 0; j < WPT; ++j) {
    const int idx = swz(threadIdx.x * 8 + j);
    float4 a = ldsA[idx];
    float4 b = ldsB[idx];
    w[j] = make_float4(a.x - b.x, a.y - b.y, a.z - b.z, a.w - b.w);
  }

  // ---- IIR over the window, pure register compute ----
  float z0 = 0.f, z1 = 0.f, z2 = 0.f, z3 = 0.f, z4 = 0.f, z5 = 0.f;
  float sum = 0.f;

  #pragma unroll
  for (int j = 0; j < WARM / 4; ++j) {    // 64 warm-up samples, discard y
    LP_STEP(w[j].x, );
    LP_STEP(w[j].y, );
    LP_STEP(w[j].z, );
    LP_STEP(w[j].w, );
  }
  #pragma unroll
  for (int j = WARM / 4; j < WPT; ++j) {  // 32 owned samples, accumulate |y|
    LP_STEP(w[j].x, sum += fabsf(y));
    LP_STEP(w[j].y, sum += fabsf(y));
    LP_STEP(w[j].z, sum += fabsf(y));
    LP_STEP(w[j].w, sum += fabsf(y));
  }

  // ---- Wave64 shuffle reduce -> LDS -> one plain store per block ----
  #pragma unroll
  for (int off = 32; off > 0; off >>= 1)
    sum += __shfl_down(sum, off);
  if (lane == 0)
    red[wv] = sum;
  __syncthreads();
  if (threadIdx.x == 0)
    partial[blk] = red[0] + red[1] + red[2] + red[3];
}

// Final reduction: 1536 partials -> d_out. One block.
__global__ __launch_bounds__(BLOCK) void lp_reduce_kernel(
    const float* __restrict__ partial, float* __restrict__ dout, float invN)
{
  __shared__ float red[BLOCK / 64];
  float sum = 0.f;
  for (int i = threadIdx.x; i < GRID; i += BLOCK)
    sum += partial[i];
  #pragma unroll
  for (int off = 32; off > 0; off >>= 1)
    sum += __shfl_down(sum, off);
  if ((threadIdx.x & 63) == 0)
    red[threadIdx.x >> 6] = sum;
  __syncthreads();
  if (threadIdx.x == 0)
    dout[0] = (red[0] + red[1] + red[2] + red[3]) * invN;
}

extern "C" void kernel_launch(void* const* d_in, const int* in_sizes, int n_in,
                              void* d_out, int out_size, void* d_ws, size_t ws_size,
                              hipStream_t stream) {
  (void)in_sizes; (void)n_in; (void)ws_size; (void)out_size;

  const float* out_p = (const float*)d_in[0];
  const float* tgt_p = (const float*)d_in[1];
  float* dout = (float*)d_out;
  float* partial = (float*)d_ws;                       // 1536 floats
  float4* zbuf = (float4*)((char*)d_ws + 8192);        // 256 B zero region

  // ---- Host-side coefficient computation (mirrors _butter_lowpass in f64,
  // then casts to f32 exactly like the reference's .astype(np.float32)). ----
  using cd = std::complex<double>;
  const int order = 6;
  const double wn = 4000.0 / 24000.0;          // CUTOFF / (0.5 * SAMPLE_RATE)
  const double fs = 2.0;
  const double warped = 2.0 * fs * std::tan(M_PI * wn / fs);

  cd p[6];
  for (int k = 0; k < order; ++k) {
    int m = -order + 1 + 2 * k;                // [-5,-3,-1,1,3,5]
    p[k] = -std::exp(cd(0.0, M_PI * m / (2.0 * order))) * warped;
  }
  double kgain = std::pow(warped, (double)order);
  const double fs2 = 2.0 * fs;

  cd pz[6];
  cd prodden(1.0, 0.0);
  for (int k = 0; k < order; ++k) {
    pz[k] = (fs2 + p[k]) / (fs2 - p[k]);
    prodden *= (fs2 - p[k]);
  }
  double kz = kgain * std::real(1.0 / prodden);

  // b = kz * poly(-ones(6)) = kz * binomial(6, i)
  const double binom[7] = {1, 6, 15, 20, 15, 6, 1};
  double bd[7];
  for (int i = 0; i < 7; ++i) bd[i] = kz * binom[i];

  // a = real(poly(pz))
  cd ac[7];
  ac[0] = cd(1.0, 0.0);
  for (int i = 1; i < 7; ++i) ac[i] = cd(0.0, 0.0);
  for (int k = 0; k < order; ++k)
    for (int i = k + 1; i >= 1; --i)
      ac[i] = ac[i] - pz[k] * ac[i - 1];

  Coefs cf;
  cf.b0 = (float)bd[0]; cf.b1 = (float)bd[1]; cf.b2 = (float)bd[2];
  cf.b3 = (float)bd[3]; cf.b4 = (float)bd[4]; cf.b5 = (float)bd[5];
  cf.b6 = (float)bd[6];
  cf.a1 = (float)std::real(ac[1]); cf.a2 = (float)std::real(ac[2]);
  cf.a3 = (float)std::real(ac[3]); cf.a4 = (float)std::real(ac[4]);
  cf.a5 = (float)std::real(ac[5]); cf.a6 = (float)std::real(ac[6]);
  cf.invN = 1.0f / (float)((double)B_ROWS * (double)T_LEN);

  hipMemsetAsync(zbuf, 0, 16 * sizeof(float4), stream);
  lp_mae_kernel<<<GRID, BLOCK, 0, stream>>>(out_p, tgt_p, zbuf, partial, cf);
  lp_reduce_kernel<<<1, BLOCK, 0, stream>>>(partial, dout, cf.invN);
}